// Round 7
// baseline (1034.090 us; speedup 1.0000x reference)
//
#include <hip/hip_runtime.h>

#define NN 100000      // nodes
#define NE 1600000     // edges
#define HD 128         // hidden dim
#define NB1 391        // ceil(NN/256) scan blocks
#define GG  782        // ceil(NN/128) gemm blocks

typedef unsigned short u16;
typedef __attribute__((ext_vector_type(8))) short bf16x8;
typedef __attribute__((ext_vector_type(4))) float f32x4;

__device__ __forceinline__ u16 f2b(float f) {            // fp32 -> bf16 RNE
    unsigned u = __builtin_bit_cast(unsigned, f);
    unsigned r = (u + 0x7FFFu + ((u >> 16) & 1u)) >> 16;
    return (u16)r;
}
__device__ __forceinline__ float b2f(u16 h) {
    unsigned u = ((unsigned)h) << 16;
    return __builtin_bit_cast(float, u);
}
__device__ __forceinline__ float lof(unsigned v) {
    return __builtin_bit_cast(float, v << 16);
}
__device__ __forceinline__ float hif(unsigned v) {
    return __builtin_bit_cast(float, v & 0xFFFF0000u);
}
__device__ __forceinline__ unsigned pack2(float a, float b) {
    return (unsigned)f2b(a) | ((unsigned)f2b(b) << 16);
}

// ===========================================================================
// CSR build. k_hist also records each edge's within-bucket offset (the
// atomicAdd return), so k_scatter needs no second atomic pass.
// ===========================================================================
__global__ __launch_bounds__(256)
void k_hist(const int* __restrict__ dst, int* __restrict__ degree,
            int* __restrict__ off) {
    int e = blockIdx.x * 256 + threadIdx.x;
    if (e < NE) off[e] = atomicAdd(degree + dst[e], 1);
}

__global__ __launch_bounds__(256)
void k_scan_blk(const int* __restrict__ degree, int* __restrict__ incl,
                int* __restrict__ bsum) {
    __shared__ int s[256];
    int t = threadIdx.x;
    int i = blockIdx.x * 256 + t;
    int v = (i < NN) ? degree[i] : 0;
    s[t] = v;
    __syncthreads();
    #pragma unroll
    for (int off = 1; off < 256; off <<= 1) {
        int tmp = (t >= off) ? s[t - off] : 0;
        __syncthreads();
        s[t] += tmp;
        __syncthreads();
    }
    if (i < NN) incl[i] = s[t];
    if (t == 255) bsum[blockIdx.x] = s[255];
}

__global__ __launch_bounds__(512)
void k_scan_top(const int* __restrict__ bsum, int* __restrict__ bscan) {
    __shared__ int s[512];
    int t = threadIdx.x;
    s[t] = (t < NB1) ? bsum[t] : 0;
    __syncthreads();
    #pragma unroll
    for (int off = 1; off < 512; off <<= 1) {
        int tmp = (t >= off) ? s[t - off] : 0;
        __syncthreads();
        s[t] += tmp;
        __syncthreads();
    }
    if (t < NB1) bscan[t] = s[t];
}

__global__ __launch_bounds__(256)
void k_scan_fix(const int* __restrict__ incl, const int* __restrict__ bscan,
                int* __restrict__ rowptr) {
    int i = blockIdx.x * 256 + threadIdx.x;
    if (i < NN) {
        int off = (blockIdx.x > 0) ? bscan[blockIdx.x - 1] : 0;
        rowptr[i + 1] = incl[i] + off;
        if (i == 0) rowptr[0] = 0;
    }
}

__global__ __launch_bounds__(256)
void k_scatter(const int* __restrict__ src, const int* __restrict__ dst,
               const int* __restrict__ rowptr, const int* __restrict__ off,
               int* __restrict__ eidx) {
    int e = blockIdx.x * 256 + threadIdx.x;
    if (e < NE) {
        eidx[rowptr[dst[e]] + off[e]] = src[e];
    }
}

// ===========================================================================
// x (fp32) -> bf16
// ===========================================================================
__global__ __launch_bounds__(256)
void k_cvt(const float* __restrict__ in, u16* __restrict__ out, int n4) {
    for (int i = blockIdx.x * 256 + threadIdx.x; i < n4; i += gridDim.x * 256) {
        float4 v = reinterpret_cast<const float4*>(in)[i];
        uint2 o;
        o.x = pack2(v.x, v.y);
        o.y = pack2(v.z, v.w);
        *reinterpret_cast<uint2*>(out + (size_t)i * 4) = o;
    }
}

// ===========================================================================
// CSR aggregation: bf16 gather, fp32 accumulate, bf16 out.
//   out[n] = (1+eps)*x[n] + sum_{src in N(n)} x[src]
// One wave per node; 4-edge ILP unroll.
// ===========================================================================
template<int F>
__global__ __launch_bounds__(64)
void k_aggr(const u16* __restrict__ x, const int* __restrict__ rowptr,
            const int* __restrict__ eidx, const float* __restrict__ epsp,
            u16* __restrict__ out) {
    const int n = blockIdx.x;
    const int t = threadIdx.x;
    const int p0 = rowptr[n], p1 = rowptr[n + 1];
    const float e1 = 1.0f + epsp[0];

    if constexpr (F == 128) {
        const unsigned off = 2u * t;
        float a0 = 0.f, a1 = 0.f, c0 = 0.f, c1 = 0.f;
        int p = p0;
        for (; p + 3 < p1; p += 4) {
            unsigned v0 = *reinterpret_cast<const unsigned*>(x + (size_t)eidx[p]     * 128 + off);
            unsigned v1 = *reinterpret_cast<const unsigned*>(x + (size_t)eidx[p + 1] * 128 + off);
            unsigned v2 = *reinterpret_cast<const unsigned*>(x + (size_t)eidx[p + 2] * 128 + off);
            unsigned v3 = *reinterpret_cast<const unsigned*>(x + (size_t)eidx[p + 3] * 128 + off);
            a0 += lof(v0); a1 += hif(v0);
            c0 += lof(v1); c1 += hif(v1);
            a0 += lof(v2); a1 += hif(v2);
            c0 += lof(v3); c1 += hif(v3);
        }
        for (; p < p1; ++p) {
            unsigned v0 = *reinterpret_cast<const unsigned*>(x + (size_t)eidx[p] * 128 + off);
            a0 += lof(v0); a1 += hif(v0);
        }
        unsigned xs = *reinterpret_cast<const unsigned*>(x + (size_t)n * 128 + off);
        float o0 = fmaf(e1, lof(xs), a0 + c0);
        float o1 = fmaf(e1, hif(xs), a1 + c1);
        *reinterpret_cast<unsigned*>(out + (size_t)n * 128 + off) = pack2(o0, o1);
    } else {  // F == 64, one bf16 per lane
        float a0 = 0.f, a1 = 0.f;
        int p = p0;
        for (; p + 3 < p1; p += 4) {
            float x0 = b2f(x[(size_t)eidx[p]     * 64 + t]);
            float x1 = b2f(x[(size_t)eidx[p + 1] * 64 + t]);
            float x2 = b2f(x[(size_t)eidx[p + 2] * 64 + t]);
            float x3 = b2f(x[(size_t)eidx[p + 3] * 64 + t]);
            a0 += x0 + x2; a1 += x1 + x3;
        }
        for (; p < p1; ++p) a0 += b2f(x[(size_t)eidx[p] * 64 + t]);
        float xs = b2f(x[(size_t)n * 64 + t]);
        out[(size_t)n * 64 + t] = f2b(fmaf(e1, xs, a0 + a1));
    }
}

// ===========================================================================
// MFMA GEMM: C[N x 128] = Pro(A[N x K]) @ W[K x 128] + bias
// Swapped operands: D = mfma(W_frag, feat_frag); thread l holds
//   C[m = mbase+mb*16+(l&15)][n = nb*16+(l>>4)*4+r]
// W fp32 staged in LDS as hi/lo bf16 [n][K], XOR-swizzled.
// ABV 1: A is bf16 (pre-rounded) -> 2 MFMAs (Whi,Wlo) x a.
// ABV 0: A fp32 -> split a into hi/lo -> 3 MFMAs.
// PRO 1: feat := relu(af*feat + bf) in fp32 (BN fused).
// STATS 1: emit per-block column sum/sumsq partials (pre-activation y).
// OM: 0 fp32 out, 1 bf16 out, 2 head (fuse relu + @w2 + b2 -> out[N x 2]).
// EPI 1: relu before store (OM 0/1).
// ===========================================================================
template<int K, int PRO, int EPI, int OM, int ABV, int STATS>
__global__ __launch_bounds__(256)
void k_gemm(const void* __restrict__ Av,
            const float* __restrict__ af,
            const float* __restrict__ bff,
            const float* __restrict__ W,
            const float* __restrict__ bias,
            void* __restrict__ Cout,
            float* __restrict__ partial,
            const float* __restrict__ w2,
            const float* __restrict__ b2) {
    __shared__ u16 Whi[128 * K];
    __shared__ u16 Wlo[128 * K];
    __shared__ float redS[4][128];
    __shared__ float redQ[4][128];

    const int t = threadIdx.x;
    const int l = t & 63;
    const int w = t >> 6;
    const int mbase = blockIdx.x * 128 + w * 32;
    const int l15 = l & 15;
    const int lg = l >> 4;           // 0..3

    // ---- stage W -> hi/lo bf16 [n][K], swizzled ----
    for (int idx = t; idx < K * 32; idx += 256) {
        int k  = idx >> 5;
        int n0 = (idx & 31) * 4;
        float4 wv = *reinterpret_cast<const float4*>(W + (size_t)k * 128 + n0);
        float wa[4] = {wv.x, wv.y, wv.z, wv.w};
        #pragma unroll
        for (int j = 0; j < 4; ++j) {
            int n = n0 + j;
            int byte = n * (2 * K) + k * 2;
            byte ^= ((n & 7) << 4);
            u16 hi = f2b(wa[j]);
            u16 lo = f2b(wa[j] - b2f(hi));
            *reinterpret_cast<u16*>(reinterpret_cast<char*>(Whi) + byte) = hi;
            *reinterpret_cast<u16*>(reinterpret_cast<char*>(Wlo) + byte) = lo;
        }
    }
    __syncthreads();

    f32x4 acc[2][8];
    #pragma unroll
    for (int i = 0; i < 2; ++i)
        #pragma unroll
        for (int j = 0; j < 8; ++j) acc[i][j] = (f32x4){0.f, 0.f, 0.f, 0.f};

    #pragma unroll
    for (int kc = 0; kc < K / 32; ++kc) {
        bf16x8 whi[8], wlo[8];
        #pragma unroll
        for (int nb = 0; nb < 8; ++nb) {
            int n = nb * 16 + l15;
            int byte = n * (2 * K) + kc * 64 + lg * 16;
            byte ^= ((n & 7) << 4);
            whi[nb] = *reinterpret_cast<const bf16x8*>(
                reinterpret_cast<const char*>(Whi) + byte);
            wlo[nb] = *reinterpret_cast<const bf16x8*>(
                reinterpret_cast<const char*>(Wlo) + byte);
        }
        float aa[8], bb[8];
        if (PRO == 1) {
            int kk = kc * 32 + lg * 8;
            float4 x0 = *reinterpret_cast<const float4*>(af + kk);
            float4 x1 = *reinterpret_cast<const float4*>(af + kk + 4);
            float4 y0 = *reinterpret_cast<const float4*>(bff + kk);
            float4 y1 = *reinterpret_cast<const float4*>(bff + kk + 4);
            aa[0] = x0.x; aa[1] = x0.y; aa[2] = x0.z; aa[3] = x0.w;
            aa[4] = x1.x; aa[5] = x1.y; aa[6] = x1.z; aa[7] = x1.w;
            bb[0] = y0.x; bb[1] = y0.y; bb[2] = y0.z; bb[3] = y0.w;
            bb[4] = y1.x; bb[5] = y1.y; bb[6] = y1.z; bb[7] = y1.w;
        }
        #pragma unroll
        for (int mb = 0; mb < 2; ++mb) {
            int m = mbase + mb * 16 + l15;
            if (ABV == 1) {
                // A already bf16: direct fragment, 2 MFMAs (W hi+lo)
                bf16x8 ff = {};
                if (m < NN)
                    ff = *reinterpret_cast<const bf16x8*>(
                        (const u16*)Av + (size_t)m * K + kc * 32 + lg * 8);
                #pragma unroll
                for (int nb = 0; nb < 8; ++nb) {
                    acc[mb][nb] = __builtin_amdgcn_mfma_f32_16x16x32_bf16(
                        whi[nb], ff, acc[mb][nb], 0, 0, 0);
                    acc[mb][nb] = __builtin_amdgcn_mfma_f32_16x16x32_bf16(
                        wlo[nb], ff, acc[mb][nb], 0, 0, 0);
                }
            } else {
                float av[8] = {0.f, 0.f, 0.f, 0.f, 0.f, 0.f, 0.f, 0.f};
                if (m < NN) {
                    const float* ap = (const float*)Av + (size_t)m * K + kc * 32 + lg * 8;
                    float4 x0 = *reinterpret_cast<const float4*>(ap);
                    float4 x1 = *reinterpret_cast<const float4*>(ap + 4);
                    av[0] = x0.x; av[1] = x0.y; av[2] = x0.z; av[3] = x0.w;
                    av[4] = x1.x; av[5] = x1.y; av[6] = x1.z; av[7] = x1.w;
                }
                if (PRO == 1) {
                    #pragma unroll
                    for (int j = 0; j < 8; ++j)
                        av[j] = fmaxf(fmaf(aa[j], av[j], bb[j]), 0.f);
                }
                union { bf16x8 v; u16 s[8]; } uh, ul;
                #pragma unroll
                for (int j = 0; j < 8; ++j) {
                    u16 hi = f2b(av[j]);
                    uh.s[j] = hi;
                    ul.s[j] = f2b(av[j] - b2f(hi));
                }
                #pragma unroll
                for (int nb = 0; nb < 8; ++nb) {
                    acc[mb][nb] = __builtin_amdgcn_mfma_f32_16x16x32_bf16(
                        whi[nb], uh.v, acc[mb][nb], 0, 0, 0);
                    acc[mb][nb] = __builtin_amdgcn_mfma_f32_16x16x32_bf16(
                        whi[nb], ul.v, acc[mb][nb], 0, 0, 0);
                    acc[mb][nb] = __builtin_amdgcn_mfma_f32_16x16x32_bf16(
                        wlo[nb], uh.v, acc[mb][nb], 0, 0, 0);
                }
            }
        }
    }

    // ---- epilogue ----
    if (OM == 2) {
        // head: out[m][j] = relu(y[m][:]) @ w2 + b2
        float o00 = 0.f, o01 = 0.f, o10 = 0.f, o11 = 0.f;
        #pragma unroll
        for (int nb = 0; nb < 8; ++nb) {
            int n0 = nb * 16 + lg * 4;
            float4 b4 = *reinterpret_cast<const float4*>(bias + n0);
            float bv[4] = {b4.x, b4.y, b4.z, b4.w};
            #pragma unroll
            for (int r = 0; r < 4; ++r) {
                int n = n0 + r;
                float w20 = w2[n * 2], w21 = w2[n * 2 + 1];
                float v0 = fmaxf(acc[0][nb][r] + bv[r], 0.f);
                float v1 = fmaxf(acc[1][nb][r] + bv[r], 0.f);
                o00 = fmaf(v0, w20, o00); o01 = fmaf(v0, w21, o01);
                o10 = fmaf(v1, w20, o10); o11 = fmaf(v1, w21, o11);
            }
        }
        o00 += __shfl_xor(o00, 16); o00 += __shfl_xor(o00, 32);
        o01 += __shfl_xor(o01, 16); o01 += __shfl_xor(o01, 32);
        o10 += __shfl_xor(o10, 16); o10 += __shfl_xor(o10, 32);
        o11 += __shfl_xor(o11, 16); o11 += __shfl_xor(o11, 32);
        if (lg == 0) {
            float bb0 = b2[0], bb1 = b2[1];
            float* outp = (float*)Cout;
            int m0 = mbase + l15, m1 = mbase + 16 + l15;
            if (m0 < NN)
                *reinterpret_cast<float2*>(outp + (size_t)m0 * 2) =
                    make_float2(o00 + bb0, o01 + bb1);
            if (m1 < NN)
                *reinterpret_cast<float2*>(outp + (size_t)m1 * 2) =
                    make_float2(o10 + bb0, o11 + bb1);
        }
        return;
    }

    #pragma unroll
    for (int nb = 0; nb < 8; ++nb) {
        int n0 = nb * 16 + lg * 4;
        float4 b4 = *reinterpret_cast<const float4*>(bias + n0);
        float bv[4] = {b4.x, b4.y, b4.z, b4.w};
        float vs[2][4];
        #pragma unroll
        for (int mb = 0; mb < 2; ++mb) {
            int m = mbase + mb * 16 + l15;
            #pragma unroll
            for (int r = 0; r < 4; ++r)
                vs[mb][r] = (m < NN) ? (acc[mb][nb][r] + bv[r]) : 0.f;
        }
        if (STATS == 1) {
            #pragma unroll
            for (int r = 0; r < 4; ++r) {
                float s = vs[0][r] + vs[1][r];
                float q = vs[0][r] * vs[0][r] + vs[1][r] * vs[1][r];
                s += __shfl_xor(s, 1); q += __shfl_xor(q, 1);
                s += __shfl_xor(s, 2); q += __shfl_xor(q, 2);
                s += __shfl_xor(s, 4); q += __shfl_xor(q, 4);
                s += __shfl_xor(s, 8); q += __shfl_xor(q, 8);
                if (l15 == 0) {
                    int n = n0 + r;
                    redS[w][n] = s;
                    redQ[w][n] = q;
                }
            }
        }
        #pragma unroll
        for (int mb = 0; mb < 2; ++mb) {
            int m = mbase + mb * 16 + l15;
            if (m >= NN) continue;
            float v0 = vs[mb][0], v1 = vs[mb][1], v2 = vs[mb][2], v3 = vs[mb][3];
            if (EPI == 1) {
                v0 = fmaxf(v0, 0.f); v1 = fmaxf(v1, 0.f);
                v2 = fmaxf(v2, 0.f); v3 = fmaxf(v3, 0.f);
            }
            if (OM == 1) {
                uint2 o;
                o.x = pack2(v0, v1);
                o.y = pack2(v2, v3);
                *reinterpret_cast<uint2*>((u16*)Cout + (size_t)m * 128 + n0) = o;
            } else {
                float4 o = make_float4(v0, v1, v2, v3);
                *reinterpret_cast<float4*>((float*)Cout + (size_t)m * 128 + n0) = o;
            }
        }
    }

    if (STATS == 1) {
        __syncthreads();
        if (t < 128) {
            float s = redS[0][t] + redS[1][t] + redS[2][t] + redS[3][t];
            float q = redQ[0][t] + redQ[1][t] + redQ[2][t] + redQ[3][t];
            partial[(size_t)blockIdx.x * 256 + t] = s;
            partial[(size_t)blockIdx.x * 256 + 128 + t] = q;
        }
    }
}

// ===========================================================================
// Reduce per-block stats partials -> BN scale/shift (double accumulation).
// ===========================================================================
__global__ __launch_bounds__(128)
void k_bnfin2(const float* __restrict__ partial,
              const float* __restrict__ g, const float* __restrict__ be,
              float* __restrict__ af, float* __restrict__ bf) {
    int c = threadIdx.x;
    double S = 0.0, Q = 0.0;
    for (int b = 0; b < GG; ++b) {
        S += (double)partial[(size_t)b * 256 + c];
        Q += (double)partial[(size_t)b * 256 + 128 + c];
    }
    double mu  = S / (double)NN;
    double var = Q / (double)NN - mu * mu;
    double a   = (double)g[c] / sqrt(var + 1e-5);
    af[c] = (float)a;
    bf[c] = be[c] - (float)(mu * a);
}

// ===========================================================================
extern "C" void kernel_launch(void* const* d_in, const int* in_sizes, int n_in,
                              void* d_out, int out_size, void* d_ws, size_t ws_size,
                              hipStream_t stream) {
    const float* x  = (const float*)d_in[0];
    const int*   ei = (const int*)d_in[1];
    const int* src = ei;
    const int* dst = ei + NE;
    auto P = [&](int i) { return (const float*)d_in[i]; };

    const size_t BUFF = (size_t)NN * HD * sizeof(float);  // 51.2 MB fp32
    const size_t BUFH = (size_t)NN * HD * sizeof(u16);    // 25.6 MB bf16
    char* ws = (char*)d_ws;
    u16*   gB   = (u16*)(ws);                             // bf16 [NN][128] lin2 out
    u16*   aggB = (u16*)(ws + BUFH);                      // bf16 [NN][128] aggr out
    float* yF   = (float*)(ws + 2 * BUFH);                // fp32 [NN][128] lin1 out
    float* hF   = (float*)(ws + 2 * BUFH + BUFF);         // fp32 [NN][128] L2 out
    u16*   xb   = (u16*)(ws + 2 * BUFH + 2 * BUFF);       // bf16 [NN][64]
    char*  sb   = ws + 2 * BUFH + 2 * BUFF + (size_t)NN * 64 * sizeof(u16);
    float* partial = (float*)sb;                          // [GG][256]
    float* af = (float*)(sb + (size_t)GG * 256 * 4);
    float* bf = af + 128;
    int* degree = (int*)(af + 256);
    int* incl   = degree + NN;
    int* bsum   = incl + NN;
    int* bscan  = bsum + 512;
    int* rowptr = bscan + 512;
    int* eoff   = rowptr + NN + 2;
    int* eidx   = eoff + NE;

    const int EGRID = (NE + 255) / 256;

    // ---- build CSR (dst-sorted) ----
    hipMemsetAsync(degree, 0, NN * sizeof(int), stream);
    k_hist<<<EGRID, 256, 0, stream>>>(dst, degree, eoff);
    k_scan_blk<<<NB1, 256, 0, stream>>>(degree, incl, bsum);
    k_scan_top<<<1, 512, 0, stream>>>(bsum, bscan);
    k_scan_fix<<<NB1, 256, 0, stream>>>(incl, bscan, rowptr);
    k_scatter<<<EGRID, 256, 0, stream>>>(src, dst, rowptr, eoff, eidx);

    // ---- x -> bf16 ----
    k_cvt<<<2048, 256, 0, stream>>>(x, xb, NN * 64 / 4);

    // ---- layer 0 (K = 64) ----
    k_aggr<64><<<NN, 64, 0, stream>>>(xb, rowptr, eidx, P(8), aggB);
    k_gemm<64, 0, 0, 0, 1, 1><<<GG, 256, 0, stream>>>(
        aggB, nullptr, nullptr, P(2), P(3), yF, partial, nullptr, nullptr);
    k_bnfin2<<<1, 128, 0, stream>>>(partial, P(4), P(5), af, bf);
    k_gemm<128, 1, 1, 1, 0, 0><<<GG, 256, 0, stream>>>(
        yF, af, bf, P(6), P(7), gB, nullptr, nullptr, nullptr);

    // ---- layer 1 ----
    k_aggr<128><<<NN, 64, 0, stream>>>(gB, rowptr, eidx, P(15), aggB);
    k_gemm<128, 0, 0, 0, 1, 1><<<GG, 256, 0, stream>>>(
        aggB, nullptr, nullptr, P(9), P(10), yF, partial, nullptr, nullptr);
    k_bnfin2<<<1, 128, 0, stream>>>(partial, P(11), P(12), af, bf);
    k_gemm<128, 1, 1, 1, 0, 0><<<GG, 256, 0, stream>>>(
        yF, af, bf, P(13), P(14), gB, nullptr, nullptr, nullptr);

    // ---- layer 2 ----
    k_aggr<128><<<NN, 64, 0, stream>>>(gB, rowptr, eidx, P(22), aggB);
    k_gemm<128, 0, 0, 0, 1, 1><<<GG, 256, 0, stream>>>(
        aggB, nullptr, nullptr, P(16), P(17), yF, partial, nullptr, nullptr);
    k_bnfin2<<<1, 128, 0, stream>>>(partial, P(18), P(19), af, bf);
    k_gemm<128, 1, 1, 0, 0, 0><<<GG, 256, 0, stream>>>(
        yF, af, bf, P(20), P(21), hF, nullptr, nullptr, nullptr);

    // ---- head (lin1 + relu + lin2 fused) ----
    k_gemm<128, 0, 1, 2, 0, 0><<<GG, 256, 0, stream>>>(
        hF, nullptr, nullptr, P(23), P(24), (float*)d_out, nullptr, P(25), P(26));
}

// Round 8
// 735.769 us; speedup vs baseline: 1.4055x; 1.4055x over previous
//
#include <hip/hip_runtime.h>

#define NN 100000      // nodes
#define NE 1600000     // edges
#define HD 128         // hidden dim
#define NB1 391        // ceil(NN/256) scan blocks
#define GG  782        // ceil(NN/128) gemm blocks

typedef unsigned short u16;
typedef __attribute__((ext_vector_type(8))) short bf16x8;
typedef __attribute__((ext_vector_type(4))) float f32x4;

__device__ __forceinline__ u16 f2b(float f) {            // fp32 -> bf16 RNE
    unsigned u = __builtin_bit_cast(unsigned, f);
    unsigned r = (u + 0x7FFFu + ((u >> 16) & 1u)) >> 16;
    return (u16)r;
}
__device__ __forceinline__ float b2f(u16 h) {
    unsigned u = ((unsigned)h) << 16;
    return __builtin_bit_cast(float, u);
}
__device__ __forceinline__ float lof(unsigned v) {
    return __builtin_bit_cast(float, v << 16);
}
__device__ __forceinline__ float hif(unsigned v) {
    return __builtin_bit_cast(float, v & 0xFFFF0000u);
}
__device__ __forceinline__ unsigned pack2(float a, float b) {
    return (unsigned)f2b(a) | ((unsigned)f2b(b) << 16);
}

// ===========================================================================
// CSR build. k_hist also records each edge's within-bucket offset (the
// atomicAdd return), so k_scatter needs no second atomic pass.
// ===========================================================================
__global__ __launch_bounds__(256)
void k_hist(const int* __restrict__ dst, int* __restrict__ degree,
            int* __restrict__ off) {
    int e = blockIdx.x * 256 + threadIdx.x;
    if (e < NE) off[e] = atomicAdd(degree + dst[e], 1);
}

__global__ __launch_bounds__(256)
void k_scan_blk(const int* __restrict__ degree, int* __restrict__ incl,
                int* __restrict__ bsum) {
    __shared__ int s[256];
    int t = threadIdx.x;
    int i = blockIdx.x * 256 + t;
    int v = (i < NN) ? degree[i] : 0;
    s[t] = v;
    __syncthreads();
    #pragma unroll
    for (int off = 1; off < 256; off <<= 1) {
        int tmp = (t >= off) ? s[t - off] : 0;
        __syncthreads();
        s[t] += tmp;
        __syncthreads();
    }
    if (i < NN) incl[i] = s[t];
    if (t == 255) bsum[blockIdx.x] = s[255];
}

__global__ __launch_bounds__(512)
void k_scan_top(const int* __restrict__ bsum, int* __restrict__ bscan) {
    __shared__ int s[512];
    int t = threadIdx.x;
    s[t] = (t < NB1) ? bsum[t] : 0;
    __syncthreads();
    #pragma unroll
    for (int off = 1; off < 512; off <<= 1) {
        int tmp = (t >= off) ? s[t - off] : 0;
        __syncthreads();
        s[t] += tmp;
        __syncthreads();
    }
    if (t < NB1) bscan[t] = s[t];
}

__global__ __launch_bounds__(256)
void k_scan_fix(const int* __restrict__ incl, const int* __restrict__ bscan,
                int* __restrict__ rowptr) {
    int i = blockIdx.x * 256 + threadIdx.x;
    if (i < NN) {
        int off = (blockIdx.x > 0) ? bscan[blockIdx.x - 1] : 0;
        rowptr[i + 1] = incl[i] + off;
        if (i == 0) rowptr[0] = 0;
    }
}

__global__ __launch_bounds__(256)
void k_scatter(const int* __restrict__ src, const int* __restrict__ dst,
               const int* __restrict__ rowptr, const int* __restrict__ off,
               int* __restrict__ eidx) {
    int e = blockIdx.x * 256 + threadIdx.x;
    if (e < NE) {
        eidx[rowptr[dst[e]] + off[e]] = src[e];
    }
}

// ===========================================================================
// x (fp32) -> bf16
// ===========================================================================
__global__ __launch_bounds__(256)
void k_cvt(const float* __restrict__ in, u16* __restrict__ out, int n4) {
    for (int i = blockIdx.x * 256 + threadIdx.x; i < n4; i += gridDim.x * 256) {
        float4 v = reinterpret_cast<const float4*>(in)[i];
        uint2 o;
        o.x = pack2(v.x, v.y);
        o.y = pack2(v.z, v.w);
        *reinterpret_cast<uint2*>(out + (size_t)i * 4) = o;
    }
}

// ===========================================================================
// CSR aggregation: bf16 gather, fp32 accumulate, bf16 out.
//   out[n] = (1+eps)*x[n] + sum_{src in N(n)} x[src]
// One wave per node; 4-edge ILP unroll.
// ===========================================================================
template<int F>
__global__ __launch_bounds__(64)
void k_aggr(const u16* __restrict__ x, const int* __restrict__ rowptr,
            const int* __restrict__ eidx, const float* __restrict__ epsp,
            u16* __restrict__ out) {
    const int n = blockIdx.x;
    const int t = threadIdx.x;
    const int p0 = rowptr[n], p1 = rowptr[n + 1];
    const float e1 = 1.0f + epsp[0];

    if constexpr (F == 128) {
        const unsigned off = 2u * t;
        float a0 = 0.f, a1 = 0.f, c0 = 0.f, c1 = 0.f;
        int p = p0;
        for (; p + 3 < p1; p += 4) {
            unsigned v0 = *reinterpret_cast<const unsigned*>(x + (size_t)eidx[p]     * 128 + off);
            unsigned v1 = *reinterpret_cast<const unsigned*>(x + (size_t)eidx[p + 1] * 128 + off);
            unsigned v2 = *reinterpret_cast<const unsigned*>(x + (size_t)eidx[p + 2] * 128 + off);
            unsigned v3 = *reinterpret_cast<const unsigned*>(x + (size_t)eidx[p + 3] * 128 + off);
            a0 += lof(v0); a1 += hif(v0);
            c0 += lof(v1); c1 += hif(v1);
            a0 += lof(v2); a1 += hif(v2);
            c0 += lof(v3); c1 += hif(v3);
        }
        for (; p < p1; ++p) {
            unsigned v0 = *reinterpret_cast<const unsigned*>(x + (size_t)eidx[p] * 128 + off);
            a0 += lof(v0); a1 += hif(v0);
        }
        unsigned xs = *reinterpret_cast<const unsigned*>(x + (size_t)n * 128 + off);
        float o0 = fmaf(e1, lof(xs), a0 + c0);
        float o1 = fmaf(e1, hif(xs), a1 + c1);
        *reinterpret_cast<unsigned*>(out + (size_t)n * 128 + off) = pack2(o0, o1);
    } else {  // F == 64, one bf16 per lane
        float a0 = 0.f, a1 = 0.f;
        int p = p0;
        for (; p + 3 < p1; p += 4) {
            float x0 = b2f(x[(size_t)eidx[p]     * 64 + t]);
            float x1 = b2f(x[(size_t)eidx[p + 1] * 64 + t]);
            float x2 = b2f(x[(size_t)eidx[p + 2] * 64 + t]);
            float x3 = b2f(x[(size_t)eidx[p + 3] * 64 + t]);
            a0 += x0 + x2; a1 += x1 + x3;
        }
        for (; p < p1; ++p) a0 += b2f(x[(size_t)eidx[p] * 64 + t]);
        float xs = b2f(x[(size_t)n * 64 + t]);
        out[(size_t)n * 64 + t] = f2b(fmaf(e1, xs, a0 + a1));
    }
}

// ===========================================================================
// MFMA GEMM: C[N x 128] = Pro(A[N x K]) @ W[K x 128] + bias
// Swapped operands: D = mfma(W_frag, feat_frag); thread l holds
//   C[m = mbase+mb*16+(l&15)][n = nb*16+(l>>4)*4+r]
// W fp32 staged in LDS as hi/lo bf16 [n][K], XOR-swizzled.
// ABV 1: A is bf16 (pre-rounded) -> 2 MFMAs (Whi,Wlo) x a.
// ABV 0: A fp32 -> split a into hi/lo -> 3 MFMAs.
// PRO 1: feat := relu(af*feat + bf) in fp32 (BN fused).
// STATS 1: emit per-block column sum/sumsq partials (pre-activation y).
// OM: 0 fp32 out, 1 bf16 out, 2 head (fuse relu + @w2 + b2 -> out[N x 2]).
// EPI 1: relu before store (OM 0/1).
// ===========================================================================
template<int K, int PRO, int EPI, int OM, int ABV, int STATS>
__global__ __launch_bounds__(256)
void k_gemm(const void* __restrict__ Av,
            const float* __restrict__ af,
            const float* __restrict__ bff,
            const float* __restrict__ W,
            const float* __restrict__ bias,
            void* __restrict__ Cout,
            float* __restrict__ partial,
            const float* __restrict__ w2,
            const float* __restrict__ b2) {
    __shared__ u16 Whi[128 * K];
    __shared__ u16 Wlo[128 * K];
    __shared__ float redS[4][128];
    __shared__ float redQ[4][128];

    const int t = threadIdx.x;
    const int l = t & 63;
    const int w = t >> 6;
    const int mbase = blockIdx.x * 128 + w * 32;
    const int l15 = l & 15;
    const int lg = l >> 4;           // 0..3

    // ---- stage W -> hi/lo bf16 [n][K], swizzled ----
    for (int idx = t; idx < K * 32; idx += 256) {
        int k  = idx >> 5;
        int n0 = (idx & 31) * 4;
        float4 wv = *reinterpret_cast<const float4*>(W + (size_t)k * 128 + n0);
        float wa[4] = {wv.x, wv.y, wv.z, wv.w};
        #pragma unroll
        for (int j = 0; j < 4; ++j) {
            int n = n0 + j;
            int byte = n * (2 * K) + k * 2;
            byte ^= ((n & 7) << 4);
            u16 hi = f2b(wa[j]);
            u16 lo = f2b(wa[j] - b2f(hi));
            *reinterpret_cast<u16*>(reinterpret_cast<char*>(Whi) + byte) = hi;
            *reinterpret_cast<u16*>(reinterpret_cast<char*>(Wlo) + byte) = lo;
        }
    }
    __syncthreads();

    f32x4 acc[2][8];
    #pragma unroll
    for (int i = 0; i < 2; ++i)
        #pragma unroll
        for (int j = 0; j < 8; ++j) acc[i][j] = (f32x4){0.f, 0.f, 0.f, 0.f};

    #pragma unroll
    for (int kc = 0; kc < K / 32; ++kc) {
        bf16x8 whi[8], wlo[8];
        #pragma unroll
        for (int nb = 0; nb < 8; ++nb) {
            int n = nb * 16 + l15;
            int byte = n * (2 * K) + kc * 64 + lg * 16;
            byte ^= ((n & 7) << 4);
            whi[nb] = *reinterpret_cast<const bf16x8*>(
                reinterpret_cast<const char*>(Whi) + byte);
            wlo[nb] = *reinterpret_cast<const bf16x8*>(
                reinterpret_cast<const char*>(Wlo) + byte);
        }
        float aa[8], bb[8];
        if (PRO == 1) {
            int kk = kc * 32 + lg * 8;
            float4 x0 = *reinterpret_cast<const float4*>(af + kk);
            float4 x1 = *reinterpret_cast<const float4*>(af + kk + 4);
            float4 y0 = *reinterpret_cast<const float4*>(bff + kk);
            float4 y1 = *reinterpret_cast<const float4*>(bff + kk + 4);
            aa[0] = x0.x; aa[1] = x0.y; aa[2] = x0.z; aa[3] = x0.w;
            aa[4] = x1.x; aa[5] = x1.y; aa[6] = x1.z; aa[7] = x1.w;
            bb[0] = y0.x; bb[1] = y0.y; bb[2] = y0.z; bb[3] = y0.w;
            bb[4] = y1.x; bb[5] = y1.y; bb[6] = y1.z; bb[7] = y1.w;
        }
        #pragma unroll
        for (int mb = 0; mb < 2; ++mb) {
            int m = mbase + mb * 16 + l15;
            if (ABV == 1) {
                // A already bf16: direct fragment, 2 MFMAs (W hi+lo)
                bf16x8 ff = {};
                if (m < NN)
                    ff = *reinterpret_cast<const bf16x8*>(
                        (const u16*)Av + (size_t)m * K + kc * 32 + lg * 8);
                #pragma unroll
                for (int nb = 0; nb < 8; ++nb) {
                    acc[mb][nb] = __builtin_amdgcn_mfma_f32_16x16x32_bf16(
                        whi[nb], ff, acc[mb][nb], 0, 0, 0);
                    acc[mb][nb] = __builtin_amdgcn_mfma_f32_16x16x32_bf16(
                        wlo[nb], ff, acc[mb][nb], 0, 0, 0);
                }
            } else {
                float av[8] = {0.f, 0.f, 0.f, 0.f, 0.f, 0.f, 0.f, 0.f};
                if (m < NN) {
                    const float* ap = (const float*)Av + (size_t)m * K + kc * 32 + lg * 8;
                    float4 x0 = *reinterpret_cast<const float4*>(ap);
                    float4 x1 = *reinterpret_cast<const float4*>(ap + 4);
                    av[0] = x0.x; av[1] = x0.y; av[2] = x0.z; av[3] = x0.w;
                    av[4] = x1.x; av[5] = x1.y; av[6] = x1.z; av[7] = x1.w;
                }
                if (PRO == 1) {
                    #pragma unroll
                    for (int j = 0; j < 8; ++j)
                        av[j] = fmaxf(fmaf(aa[j], av[j], bb[j]), 0.f);
                }
                union { bf16x8 v; u16 s[8]; } uh, ul;
                #pragma unroll
                for (int j = 0; j < 8; ++j) {
                    u16 hi = f2b(av[j]);
                    uh.s[j] = hi;
                    ul.s[j] = f2b(av[j] - b2f(hi));
                }
                #pragma unroll
                for (int nb = 0; nb < 8; ++nb) {
                    acc[mb][nb] = __builtin_amdgcn_mfma_f32_16x16x32_bf16(
                        whi[nb], uh.v, acc[mb][nb], 0, 0, 0);
                    acc[mb][nb] = __builtin_amdgcn_mfma_f32_16x16x32_bf16(
                        whi[nb], ul.v, acc[mb][nb], 0, 0, 0);
                    acc[mb][nb] = __builtin_amdgcn_mfma_f32_16x16x32_bf16(
                        wlo[nb], uh.v, acc[mb][nb], 0, 0, 0);
                }
            }
        }
    }

    // ---- epilogue ----
    if (OM == 2) {
        // head: out[m][j] = relu(y[m][:]) @ w2 + b2
        float o00 = 0.f, o01 = 0.f, o10 = 0.f, o11 = 0.f;
        #pragma unroll
        for (int nb = 0; nb < 8; ++nb) {
            int n0 = nb * 16 + lg * 4;
            float4 b4 = *reinterpret_cast<const float4*>(bias + n0);
            float bv[4] = {b4.x, b4.y, b4.z, b4.w};
            #pragma unroll
            for (int r = 0; r < 4; ++r) {
                int n = n0 + r;
                float w20 = w2[n * 2], w21 = w2[n * 2 + 1];
                float v0 = fmaxf(acc[0][nb][r] + bv[r], 0.f);
                float v1 = fmaxf(acc[1][nb][r] + bv[r], 0.f);
                o00 = fmaf(v0, w20, o00); o01 = fmaf(v0, w21, o01);
                o10 = fmaf(v1, w20, o10); o11 = fmaf(v1, w21, o11);
            }
        }
        o00 += __shfl_xor(o00, 16); o00 += __shfl_xor(o00, 32);
        o01 += __shfl_xor(o01, 16); o01 += __shfl_xor(o01, 32);
        o10 += __shfl_xor(o10, 16); o10 += __shfl_xor(o10, 32);
        o11 += __shfl_xor(o11, 16); o11 += __shfl_xor(o11, 32);
        if (lg == 0) {
            float bb0 = b2[0], bb1 = b2[1];
            float* outp = (float*)Cout;
            int m0 = mbase + l15, m1 = mbase + 16 + l15;
            if (m0 < NN)
                *reinterpret_cast<float2*>(outp + (size_t)m0 * 2) =
                    make_float2(o00 + bb0, o01 + bb1);
            if (m1 < NN)
                *reinterpret_cast<float2*>(outp + (size_t)m1 * 2) =
                    make_float2(o10 + bb0, o11 + bb1);
        }
        return;
    }

    #pragma unroll
    for (int nb = 0; nb < 8; ++nb) {
        int n0 = nb * 16 + lg * 4;
        float4 b4 = *reinterpret_cast<const float4*>(bias + n0);
        float bv[4] = {b4.x, b4.y, b4.z, b4.w};
        float vs[2][4];
        #pragma unroll
        for (int mb = 0; mb < 2; ++mb) {
            int m = mbase + mb * 16 + l15;
            #pragma unroll
            for (int r = 0; r < 4; ++r)
                vs[mb][r] = (m < NN) ? (acc[mb][nb][r] + bv[r]) : 0.f;
        }
        if (STATS == 1) {
            #pragma unroll
            for (int r = 0; r < 4; ++r) {
                float s = vs[0][r] + vs[1][r];
                float q = vs[0][r] * vs[0][r] + vs[1][r] * vs[1][r];
                s += __shfl_xor(s, 1); q += __shfl_xor(q, 1);
                s += __shfl_xor(s, 2); q += __shfl_xor(q, 2);
                s += __shfl_xor(s, 4); q += __shfl_xor(q, 4);
                s += __shfl_xor(s, 8); q += __shfl_xor(q, 8);
                if (l15 == 0) {
                    int n = n0 + r;
                    redS[w][n] = s;
                    redQ[w][n] = q;
                }
            }
        }
        #pragma unroll
        for (int mb = 0; mb < 2; ++mb) {
            int m = mbase + mb * 16 + l15;
            if (m >= NN) continue;
            float v0 = vs[mb][0], v1 = vs[mb][1], v2 = vs[mb][2], v3 = vs[mb][3];
            if (EPI == 1) {
                v0 = fmaxf(v0, 0.f); v1 = fmaxf(v1, 0.f);
                v2 = fmaxf(v2, 0.f); v3 = fmaxf(v3, 0.f);
            }
            if (OM == 1) {
                uint2 o;
                o.x = pack2(v0, v1);
                o.y = pack2(v2, v3);
                *reinterpret_cast<uint2*>((u16*)Cout + (size_t)m * 128 + n0) = o;
            } else {
                float4 o = make_float4(v0, v1, v2, v3);
                *reinterpret_cast<float4*>((float*)Cout + (size_t)m * 128 + n0) = o;
            }
        }
    }

    if (STATS == 1) {
        __syncthreads();
        if (t < 128) {
            float s = redS[0][t] + redS[1][t] + redS[2][t] + redS[3][t];
            float q = redQ[0][t] + redQ[1][t] + redQ[2][t] + redQ[3][t];
            partial[(size_t)blockIdx.x * 256 + t] = s;
            partial[(size_t)blockIdx.x * 256 + 128 + t] = q;
        }
    }
}

// ===========================================================================
// Reduce per-block stats partials -> BN scale/shift.
// One block per column (128 blocks x 256 threads), double accumulation,
// LDS tree reduce. Replaces the serial 1-block version (was 106 us!).
// ===========================================================================
__global__ __launch_bounds__(256)
void k_bnfin2(const float* __restrict__ partial,
              const float* __restrict__ g, const float* __restrict__ be,
              float* __restrict__ af, float* __restrict__ bf) {
    const int c = blockIdx.x;    // column 0..127
    const int t = threadIdx.x;
    __shared__ double sS[256];
    __shared__ double sQ[256];
    double S = 0.0, Q = 0.0;
    for (int b = t; b < GG; b += 256) {
        S += (double)partial[(size_t)b * 256 + c];
        Q += (double)partial[(size_t)b * 256 + 128 + c];
    }
    sS[t] = S; sQ[t] = Q;
    __syncthreads();
    #pragma unroll
    for (int off = 128; off > 0; off >>= 1) {
        if (t < off) { sS[t] += sS[t + off]; sQ[t] += sQ[t + off]; }
        __syncthreads();
    }
    if (t == 0) {
        double mu  = sS[0] / (double)NN;
        double var = sQ[0] / (double)NN - mu * mu;
        double a   = (double)g[c] / sqrt(var + 1e-5);
        af[c] = (float)a;
        bf[c] = be[c] - (float)(mu * a);
    }
}

// ===========================================================================
extern "C" void kernel_launch(void* const* d_in, const int* in_sizes, int n_in,
                              void* d_out, int out_size, void* d_ws, size_t ws_size,
                              hipStream_t stream) {
    const float* x  = (const float*)d_in[0];
    const int*   ei = (const int*)d_in[1];
    const int* src = ei;
    const int* dst = ei + NE;
    auto P = [&](int i) { return (const float*)d_in[i]; };

    const size_t BUFF = (size_t)NN * HD * sizeof(float);  // 51.2 MB fp32
    const size_t BUFH = (size_t)NN * HD * sizeof(u16);    // 25.6 MB bf16
    char* ws = (char*)d_ws;
    u16*   gB   = (u16*)(ws);                             // bf16 [NN][128] lin2 out
    u16*   aggB = (u16*)(ws + BUFH);                      // bf16 [NN][128] aggr out
    float* yF   = (float*)(ws + 2 * BUFH);                // fp32 [NN][128] lin1 out
    float* hF   = (float*)(ws + 2 * BUFH + BUFF);         // fp32 [NN][128] L2 out
    u16*   xb   = (u16*)(ws + 2 * BUFH + 2 * BUFF);       // bf16 [NN][64]
    char*  sb   = ws + 2 * BUFH + 2 * BUFF + (size_t)NN * 64 * sizeof(u16);
    float* partial = (float*)sb;                          // [GG][256]
    float* af = (float*)(sb + (size_t)GG * 256 * 4);
    float* bf = af + 128;
    int* degree = (int*)(af + 256);
    int* incl   = degree + NN;
    int* bsum   = incl + NN;
    int* bscan  = bsum + 512;
    int* rowptr = bscan + 512;
    int* eoff   = rowptr + NN + 2;
    int* eidx   = eoff + NE;

    const int EGRID = (NE + 255) / 256;

    // ---- build CSR (dst-sorted) ----
    hipMemsetAsync(degree, 0, NN * sizeof(int), stream);
    k_hist<<<EGRID, 256, 0, stream>>>(dst, degree, eoff);
    k_scan_blk<<<NB1, 256, 0, stream>>>(degree, incl, bsum);
    k_scan_top<<<1, 512, 0, stream>>>(bsum, bscan);
    k_scan_fix<<<NB1, 256, 0, stream>>>(incl, bscan, rowptr);
    k_scatter<<<EGRID, 256, 0, stream>>>(src, dst, rowptr, eoff, eidx);

    // ---- x -> bf16 ----
    k_cvt<<<2048, 256, 0, stream>>>(x, xb, NN * 64 / 4);

    // ---- layer 0 (K = 64) ----
    k_aggr<64><<<NN, 64, 0, stream>>>(xb, rowptr, eidx, P(8), aggB);
    k_gemm<64, 0, 0, 0, 1, 1><<<GG, 256, 0, stream>>>(
        aggB, nullptr, nullptr, P(2), P(3), yF, partial, nullptr, nullptr);
    k_bnfin2<<<128, 256, 0, stream>>>(partial, P(4), P(5), af, bf);
    k_gemm<128, 1, 1, 1, 0, 0><<<GG, 256, 0, stream>>>(
        yF, af, bf, P(6), P(7), gB, nullptr, nullptr, nullptr);

    // ---- layer 1 ----
    k_aggr<128><<<NN, 64, 0, stream>>>(gB, rowptr, eidx, P(15), aggB);
    k_gemm<128, 0, 0, 0, 1, 1><<<GG, 256, 0, stream>>>(
        aggB, nullptr, nullptr, P(9), P(10), yF, partial, nullptr, nullptr);
    k_bnfin2<<<128, 256, 0, stream>>>(partial, P(11), P(12), af, bf);
    k_gemm<128, 1, 1, 1, 0, 0><<<GG, 256, 0, stream>>>(
        yF, af, bf, P(13), P(14), gB, nullptr, nullptr, nullptr);

    // ---- layer 2 ----
    k_aggr<128><<<NN, 64, 0, stream>>>(gB, rowptr, eidx, P(22), aggB);
    k_gemm<128, 0, 0, 0, 1, 1><<<GG, 256, 0, stream>>>(
        aggB, nullptr, nullptr, P(16), P(17), yF, partial, nullptr, nullptr);
    k_bnfin2<<<128, 256, 0, stream>>>(partial, P(18), P(19), af, bf);
    k_gemm<128, 1, 1, 0, 0, 0><<<GG, 256, 0, stream>>>(
        yF, af, bf, P(20), P(21), hF, nullptr, nullptr, nullptr);

    // ---- head (lin1 + relu + lin2 fused) ----
    k_gemm<128, 0, 1, 2, 0, 0><<<GG, 256, 0, stream>>>(
        hF, nullptr, nullptr, P(23), P(24), (float*)d_out, nullptr, P(25), P(26));
}

// Round 9
// 711.946 us; speedup vs baseline: 1.4525x; 1.0335x over previous
//
#include <hip/hip_runtime.h>

#define NN 100000      // nodes
#define NE 1600000     // edges
#define HD 128         // hidden dim
#define GG  782        // ceil(NN/128) gemm blocks
#define NBKT 391       // node buckets of 256 -> covers 100096
#define BW_SH 8        // bucket = node >> 8

typedef unsigned short u16;
typedef __attribute__((ext_vector_type(8))) short bf16x8;
typedef __attribute__((ext_vector_type(4))) float f32x4;

__device__ __forceinline__ u16 f2b(float f) {            // fp32 -> bf16 RNE
    unsigned u = __builtin_bit_cast(unsigned, f);
    unsigned r = (u + 0x7FFFu + ((u >> 16) & 1u)) >> 16;
    return (u16)r;
}
__device__ __forceinline__ float b2f(u16 h) {
    unsigned u = ((unsigned)h) << 16;
    return __builtin_bit_cast(float, u);
}
__device__ __forceinline__ float lof(unsigned v) {
    return __builtin_bit_cast(float, v << 16);
}
__device__ __forceinline__ float hif(unsigned v) {
    return __builtin_bit_cast(float, v & 0xFFFF0000u);
}
__device__ __forceinline__ unsigned pack2(float a, float b) {
    return (unsigned)f2b(a) | ((unsigned)f2b(b) << 16);
}

// ===========================================================================
// CSR build via two-level bucket sort (no global random writes).
// Bucket b = nodes [b*256, b*256+256). Phase 1: coarse counts (LDS-private).
// Phase 2: scan bucket counts. Phase 3: scatter (src,dst) pairs to
// bucket-contiguous regions with block-claimed ranges (contiguous runs).
// Phase 4: one block per bucket -> LDS degree hist + scan -> rowptr segment
// (coalesced) + eidx scatter confined to an L2-resident 16KB window.
// ===========================================================================
__global__ __launch_bounds__(256)
void k_bcount(const int* __restrict__ dst, int* __restrict__ bucketCnt) {
    __shared__ int cnt[NBKT];
    const int t = threadIdx.x;
    for (int i = t; i < NBKT; i += 256) cnt[i] = 0;
    __syncthreads();
    int e0 = blockIdx.x * 4096 + t;
    #pragma unroll
    for (int i = 0; i < 16; ++i) {
        int e = e0 + i * 256;
        if (e < NE) atomicAdd(&cnt[dst[e] >> BW_SH], 1);
    }
    __syncthreads();
    for (int i = t; i < NBKT; i += 256)
        if (cnt[i]) atomicAdd(bucketCnt + i, cnt[i]);
}

__global__ __launch_bounds__(512)
void k_bscan(const int* __restrict__ bucketCnt, int* __restrict__ bucketBase,
             int* __restrict__ bucketCur) {
    __shared__ int s[512];
    const int t = threadIdx.x;
    int v = (t < NBKT) ? bucketCnt[t] : 0;
    s[t] = v;
    __syncthreads();
    #pragma unroll
    for (int off = 1; off < 512; off <<= 1) {
        int tmp = (t >= off) ? s[t - off] : 0;
        __syncthreads();
        s[t] += tmp;
        __syncthreads();
    }
    if (t < NBKT) {
        bucketBase[t + 1] = s[t];
        bucketCur[t] = s[t] - v;
        if (t == 0) bucketBase[0] = 0;
    }
}

__global__ __launch_bounds__(256)
void k_bscatter(const int* __restrict__ src, const int* __restrict__ dst,
                int* __restrict__ bucketCur, int2* __restrict__ pairs) {
    __shared__ int cnt[NBKT];
    __shared__ int cbase[NBKT];
    const int t = threadIdx.x;
    for (int i = t; i < NBKT; i += 256) cnt[i] = 0;
    __syncthreads();
    int e0 = blockIdx.x * 4096 + t;
    int db[16];
    #pragma unroll
    for (int i = 0; i < 16; ++i) {
        int e = e0 + i * 256;
        db[i] = (e < NE) ? dst[e] : -1;
        if (db[i] >= 0) atomicAdd(&cnt[db[i] >> BW_SH], 1);
    }
    __syncthreads();
    for (int i = t; i < NBKT; i += 256)
        cbase[i] = cnt[i] ? atomicAdd(bucketCur + i, cnt[i]) : 0;
    __syncthreads();
    for (int i = t; i < NBKT; i += 256) cnt[i] = 0;
    __syncthreads();
    #pragma unroll
    for (int i = 0; i < 16; ++i) {
        int e = e0 + i * 256;
        if (e < NE) {
            int b = db[i] >> BW_SH;
            int r = atomicAdd(&cnt[b], 1);
            pairs[cbase[b] + r] = make_int2(src[e], db[i]);
        }
    }
}

__global__ __launch_bounds__(256)
void k_bfinal(const int2* __restrict__ pairs, const int* __restrict__ bucketBase,
              int* __restrict__ rowptr, int* __restrict__ eidx) {
    __shared__ int deg[256], pfx[256], cur[256];
    const int b = blockIdx.x, t = threadIdx.x;
    const int n0 = b << BW_SH;
    const int bb = bucketBase[b], be = bucketBase[b + 1];
    deg[t] = 0;
    __syncthreads();
    for (int e = bb + t; e < be; e += 256)
        atomicAdd(&deg[pairs[e].y & 255], 1);
    __syncthreads();
    int v = deg[t];
    pfx[t] = v;
    __syncthreads();
    #pragma unroll
    for (int off = 1; off < 256; off <<= 1) {
        int tmp = (t >= off) ? pfx[t - off] : 0;
        __syncthreads();
        pfx[t] += tmp;
        __syncthreads();
    }
    int n = n0 + t;
    if (n < NN) rowptr[n + 1] = bb + pfx[t];
    if (b == 0 && t == 0) rowptr[0] = 0;
    cur[t] = bb + pfx[t] - v;
    __syncthreads();
    for (int e = bb + t; e < be; e += 256) {
        int2 p = pairs[e];
        int pos = atomicAdd(&cur[p.y & 255], 1);
        eidx[pos] = p.x;
    }
}

// ===========================================================================
// x (fp32) -> bf16
// ===========================================================================
__global__ __launch_bounds__(256)
void k_cvt(const float* __restrict__ in, u16* __restrict__ out, int n4) {
    for (int i = blockIdx.x * 256 + threadIdx.x; i < n4; i += gridDim.x * 256) {
        float4 v = reinterpret_cast<const float4*>(in)[i];
        uint2 o;
        o.x = pack2(v.x, v.y);
        o.y = pack2(v.z, v.w);
        *reinterpret_cast<uint2*>(out + (size_t)i * 4) = o;
    }
}

// ===========================================================================
// CSR aggregation: bf16 gather, fp32 accumulate, bf16 out.
//   out[n] = (1+eps)*x[n] + sum_{src in N(n)} x[src]
// One wave per node; 4-edge ILP unroll.
// ===========================================================================
template<int F>
__global__ __launch_bounds__(64)
void k_aggr(const u16* __restrict__ x, const int* __restrict__ rowptr,
            const int* __restrict__ eidx, const float* __restrict__ epsp,
            u16* __restrict__ out) {
    const int n = blockIdx.x;
    const int t = threadIdx.x;
    const int p0 = rowptr[n], p1 = rowptr[n + 1];
    const float e1 = 1.0f + epsp[0];

    if constexpr (F == 128) {
        const unsigned off = 2u * t;
        float a0 = 0.f, a1 = 0.f, c0 = 0.f, c1 = 0.f;
        int p = p0;
        for (; p + 3 < p1; p += 4) {
            unsigned v0 = *reinterpret_cast<const unsigned*>(x + (size_t)eidx[p]     * 128 + off);
            unsigned v1 = *reinterpret_cast<const unsigned*>(x + (size_t)eidx[p + 1] * 128 + off);
            unsigned v2 = *reinterpret_cast<const unsigned*>(x + (size_t)eidx[p + 2] * 128 + off);
            unsigned v3 = *reinterpret_cast<const unsigned*>(x + (size_t)eidx[p + 3] * 128 + off);
            a0 += lof(v0); a1 += hif(v0);
            c0 += lof(v1); c1 += hif(v1);
            a0 += lof(v2); a1 += hif(v2);
            c0 += lof(v3); c1 += hif(v3);
        }
        for (; p < p1; ++p) {
            unsigned v0 = *reinterpret_cast<const unsigned*>(x + (size_t)eidx[p] * 128 + off);
            a0 += lof(v0); a1 += hif(v0);
        }
        unsigned xs = *reinterpret_cast<const unsigned*>(x + (size_t)n * 128 + off);
        float o0 = fmaf(e1, lof(xs), a0 + c0);
        float o1 = fmaf(e1, hif(xs), a1 + c1);
        *reinterpret_cast<unsigned*>(out + (size_t)n * 128 + off) = pack2(o0, o1);
    } else {  // F == 64, one bf16 per lane
        float a0 = 0.f, a1 = 0.f;
        int p = p0;
        for (; p + 3 < p1; p += 4) {
            float x0 = b2f(x[(size_t)eidx[p]     * 64 + t]);
            float x1 = b2f(x[(size_t)eidx[p + 1] * 64 + t]);
            float x2 = b2f(x[(size_t)eidx[p + 2] * 64 + t]);
            float x3 = b2f(x[(size_t)eidx[p + 3] * 64 + t]);
            a0 += x0 + x2; a1 += x1 + x3;
        }
        for (; p < p1; ++p) a0 += b2f(x[(size_t)eidx[p] * 64 + t]);
        float xs = b2f(x[(size_t)n * 64 + t]);
        out[(size_t)n * 64 + t] = f2b(fmaf(e1, xs, a0 + a1));
    }
}

// ===========================================================================
// MFMA GEMM: C[N x 128] = Pro(A[N x K]) @ W[K x 128] + bias
// Swapped operands: D = mfma(W_frag, feat_frag); thread l holds
//   C[m = mbase+mb*16+(l&15)][n = nb*16+(l>>4)*4+r]
// W fp32 staged in LDS as hi/lo bf16 [n][K], XOR-swizzled.
// ABV 1: A is bf16 (pre-rounded) -> 2 MFMAs (Whi,Wlo) x a.
// ABV 0: A fp32 -> split a into hi/lo -> 3 MFMAs.
// PRO 1: feat := relu(af*feat + bf) in fp32 (BN fused).
// STATS 1: emit per-block column sum/sumsq partials (pre-activation y).
// OM: 0 fp32 out, 1 bf16 out, 2 head (fuse relu + @w2 + b2 -> out[N x 2]).
// EPI 1: relu before store (OM 0/1).
// ===========================================================================
template<int K, int PRO, int EPI, int OM, int ABV, int STATS>
__global__ __launch_bounds__(256)
void k_gemm(const void* __restrict__ Av,
            const float* __restrict__ af,
            const float* __restrict__ bff,
            const float* __restrict__ W,
            const float* __restrict__ bias,
            void* __restrict__ Cout,
            float* __restrict__ partial,
            const float* __restrict__ w2,
            const float* __restrict__ b2) {
    __shared__ u16 Whi[128 * K];
    __shared__ u16 Wlo[128 * K];
    __shared__ float redS[4][128];
    __shared__ float redQ[4][128];

    const int t = threadIdx.x;
    const int l = t & 63;
    const int w = t >> 6;
    const int mbase = blockIdx.x * 128 + w * 32;
    const int l15 = l & 15;
    const int lg = l >> 4;           // 0..3

    // ---- stage W -> hi/lo bf16 [n][K], swizzled ----
    for (int idx = t; idx < K * 32; idx += 256) {
        int k  = idx >> 5;
        int n0 = (idx & 31) * 4;
        float4 wv = *reinterpret_cast<const float4*>(W + (size_t)k * 128 + n0);
        float wa[4] = {wv.x, wv.y, wv.z, wv.w};
        #pragma unroll
        for (int j = 0; j < 4; ++j) {
            int n = n0 + j;
            int byte = n * (2 * K) + k * 2;
            byte ^= ((n & 7) << 4);
            u16 hi = f2b(wa[j]);
            u16 lo = f2b(wa[j] - b2f(hi));
            *reinterpret_cast<u16*>(reinterpret_cast<char*>(Whi) + byte) = hi;
            *reinterpret_cast<u16*>(reinterpret_cast<char*>(Wlo) + byte) = lo;
        }
    }
    __syncthreads();

    f32x4 acc[2][8];
    #pragma unroll
    for (int i = 0; i < 2; ++i)
        #pragma unroll
        for (int j = 0; j < 8; ++j) acc[i][j] = (f32x4){0.f, 0.f, 0.f, 0.f};

    #pragma unroll
    for (int kc = 0; kc < K / 32; ++kc) {
        bf16x8 whi[8], wlo[8];
        #pragma unroll
        for (int nb = 0; nb < 8; ++nb) {
            int n = nb * 16 + l15;
            int byte = n * (2 * K) + kc * 64 + lg * 16;
            byte ^= ((n & 7) << 4);
            whi[nb] = *reinterpret_cast<const bf16x8*>(
                reinterpret_cast<const char*>(Whi) + byte);
            wlo[nb] = *reinterpret_cast<const bf16x8*>(
                reinterpret_cast<const char*>(Wlo) + byte);
        }
        float aa[8], bb[8];
        if (PRO == 1) {
            int kk = kc * 32 + lg * 8;
            float4 x0 = *reinterpret_cast<const float4*>(af + kk);
            float4 x1 = *reinterpret_cast<const float4*>(af + kk + 4);
            float4 y0 = *reinterpret_cast<const float4*>(bff + kk);
            float4 y1 = *reinterpret_cast<const float4*>(bff + kk + 4);
            aa[0] = x0.x; aa[1] = x0.y; aa[2] = x0.z; aa[3] = x0.w;
            aa[4] = x1.x; aa[5] = x1.y; aa[6] = x1.z; aa[7] = x1.w;
            bb[0] = y0.x; bb[1] = y0.y; bb[2] = y0.z; bb[3] = y0.w;
            bb[4] = y1.x; bb[5] = y1.y; bb[6] = y1.z; bb[7] = y1.w;
        }
        #pragma unroll
        for (int mb = 0; mb < 2; ++mb) {
            int m = mbase + mb * 16 + l15;
            if (ABV == 1) {
                // A already bf16: direct fragment, 2 MFMAs (W hi+lo)
                bf16x8 ff = {};
                if (m < NN)
                    ff = *reinterpret_cast<const bf16x8*>(
                        (const u16*)Av + (size_t)m * K + kc * 32 + lg * 8);
                #pragma unroll
                for (int nb = 0; nb < 8; ++nb) {
                    acc[mb][nb] = __builtin_amdgcn_mfma_f32_16x16x32_bf16(
                        whi[nb], ff, acc[mb][nb], 0, 0, 0);
                    acc[mb][nb] = __builtin_amdgcn_mfma_f32_16x16x32_bf16(
                        wlo[nb], ff, acc[mb][nb], 0, 0, 0);
                }
            } else {
                float av[8] = {0.f, 0.f, 0.f, 0.f, 0.f, 0.f, 0.f, 0.f};
                if (m < NN) {
                    const float* ap = (const float*)Av + (size_t)m * K + kc * 32 + lg * 8;
                    float4 x0 = *reinterpret_cast<const float4*>(ap);
                    float4 x1 = *reinterpret_cast<const float4*>(ap + 4);
                    av[0] = x0.x; av[1] = x0.y; av[2] = x0.z; av[3] = x0.w;
                    av[4] = x1.x; av[5] = x1.y; av[6] = x1.z; av[7] = x1.w;
                }
                if (PRO == 1) {
                    #pragma unroll
                    for (int j = 0; j < 8; ++j)
                        av[j] = fmaxf(fmaf(aa[j], av[j], bb[j]), 0.f);
                }
                union { bf16x8 v; u16 s[8]; } uh, ul;
                #pragma unroll
                for (int j = 0; j < 8; ++j) {
                    u16 hi = f2b(av[j]);
                    uh.s[j] = hi;
                    ul.s[j] = f2b(av[j] - b2f(hi));
                }
                #pragma unroll
                for (int nb = 0; nb < 8; ++nb) {
                    acc[mb][nb] = __builtin_amdgcn_mfma_f32_16x16x32_bf16(
                        whi[nb], uh.v, acc[mb][nb], 0, 0, 0);
                    acc[mb][nb] = __builtin_amdgcn_mfma_f32_16x16x32_bf16(
                        whi[nb], ul.v, acc[mb][nb], 0, 0, 0);
                    acc[mb][nb] = __builtin_amdgcn_mfma_f32_16x16x32_bf16(
                        wlo[nb], uh.v, acc[mb][nb], 0, 0, 0);
                }
            }
        }
    }

    // ---- epilogue ----
    if (OM == 2) {
        // head: out[m][j] = relu(y[m][:]) @ w2 + b2
        float o00 = 0.f, o01 = 0.f, o10 = 0.f, o11 = 0.f;
        #pragma unroll
        for (int nb = 0; nb < 8; ++nb) {
            int n0 = nb * 16 + lg * 4;
            float4 b4 = *reinterpret_cast<const float4*>(bias + n0);
            float bv[4] = {b4.x, b4.y, b4.z, b4.w};
            #pragma unroll
            for (int r = 0; r < 4; ++r) {
                int n = n0 + r;
                float w20 = w2[n * 2], w21 = w2[n * 2 + 1];
                float v0 = fmaxf(acc[0][nb][r] + bv[r], 0.f);
                float v1 = fmaxf(acc[1][nb][r] + bv[r], 0.f);
                o00 = fmaf(v0, w20, o00); o01 = fmaf(v0, w21, o01);
                o10 = fmaf(v1, w20, o10); o11 = fmaf(v1, w21, o11);
            }
        }
        o00 += __shfl_xor(o00, 16); o00 += __shfl_xor(o00, 32);
        o01 += __shfl_xor(o01, 16); o01 += __shfl_xor(o01, 32);
        o10 += __shfl_xor(o10, 16); o10 += __shfl_xor(o10, 32);
        o11 += __shfl_xor(o11, 16); o11 += __shfl_xor(o11, 32);
        if (lg == 0) {
            float bb0 = b2[0], bb1 = b2[1];
            float* outp = (float*)Cout;
            int m0 = mbase + l15, m1 = mbase + 16 + l15;
            if (m0 < NN)
                *reinterpret_cast<float2*>(outp + (size_t)m0 * 2) =
                    make_float2(o00 + bb0, o01 + bb1);
            if (m1 < NN)
                *reinterpret_cast<float2*>(outp + (size_t)m1 * 2) =
                    make_float2(o10 + bb0, o11 + bb1);
        }
        return;
    }

    #pragma unroll
    for (int nb = 0; nb < 8; ++nb) {
        int n0 = nb * 16 + lg * 4;
        float4 b4 = *reinterpret_cast<const float4*>(bias + n0);
        float bv[4] = {b4.x, b4.y, b4.z, b4.w};
        float vs[2][4];
        #pragma unroll
        for (int mb = 0; mb < 2; ++mb) {
            int m = mbase + mb * 16 + l15;
            #pragma unroll
            for (int r = 0; r < 4; ++r)
                vs[mb][r] = (m < NN) ? (acc[mb][nb][r] + bv[r]) : 0.f;
        }
        if (STATS == 1) {
            #pragma unroll
            for (int r = 0; r < 4; ++r) {
                float s = vs[0][r] + vs[1][r];
                float q = vs[0][r] * vs[0][r] + vs[1][r] * vs[1][r];
                s += __shfl_xor(s, 1); q += __shfl_xor(q, 1);
                s += __shfl_xor(s, 2); q += __shfl_xor(q, 2);
                s += __shfl_xor(s, 4); q += __shfl_xor(q, 4);
                s += __shfl_xor(s, 8); q += __shfl_xor(q, 8);
                if (l15 == 0) {
                    int n = n0 + r;
                    redS[w][n] = s;
                    redQ[w][n] = q;
                }
            }
        }
        #pragma unroll
        for (int mb = 0; mb < 2; ++mb) {
            int m = mbase + mb * 16 + l15;
            if (m >= NN) continue;
            float v0 = vs[mb][0], v1 = vs[mb][1], v2 = vs[mb][2], v3 = vs[mb][3];
            if (EPI == 1) {
                v0 = fmaxf(v0, 0.f); v1 = fmaxf(v1, 0.f);
                v2 = fmaxf(v2, 0.f); v3 = fmaxf(v3, 0.f);
            }
            if (OM == 1) {
                uint2 o;
                o.x = pack2(v0, v1);
                o.y = pack2(v2, v3);
                *reinterpret_cast<uint2*>((u16*)Cout + (size_t)m * 128 + n0) = o;
            } else {
                float4 o = make_float4(v0, v1, v2, v3);
                *reinterpret_cast<float4*>((float*)Cout + (size_t)m * 128 + n0) = o;
            }
        }
    }

    if (STATS == 1) {
        __syncthreads();
        if (t < 128) {
            float s = redS[0][t] + redS[1][t] + redS[2][t] + redS[3][t];
            float q = redQ[0][t] + redQ[1][t] + redQ[2][t] + redQ[3][t];
            partial[(size_t)blockIdx.x * 256 + t] = s;
            partial[(size_t)blockIdx.x * 256 + 128 + t] = q;
        }
    }
}

// ===========================================================================
// Reduce per-block stats partials -> BN scale/shift.
// One block per column (128 blocks x 256 threads), double accumulation.
// ===========================================================================
__global__ __launch_bounds__(256)
void k_bnfin2(const float* __restrict__ partial,
              const float* __restrict__ g, const float* __restrict__ be,
              float* __restrict__ af, float* __restrict__ bf) {
    const int c = blockIdx.x;    // column 0..127
    const int t = threadIdx.x;
    __shared__ double sS[256];
    __shared__ double sQ[256];
    double S = 0.0, Q = 0.0;
    for (int b = t; b < GG; b += 256) {
        S += (double)partial[(size_t)b * 256 + c];
        Q += (double)partial[(size_t)b * 256 + 128 + c];
    }
    sS[t] = S; sQ[t] = Q;
    __syncthreads();
    #pragma unroll
    for (int off = 128; off > 0; off >>= 1) {
        if (t < off) { sS[t] += sS[t + off]; sQ[t] += sQ[t + off]; }
        __syncthreads();
    }
    if (t == 0) {
        double mu  = sS[0] / (double)NN;
        double var = sQ[0] / (double)NN - mu * mu;
        double a   = (double)g[c] / sqrt(var + 1e-5);
        af[c] = (float)a;
        bf[c] = be[c] - (float)(mu * a);
    }
}

// ===========================================================================
extern "C" void kernel_launch(void* const* d_in, const int* in_sizes, int n_in,
                              void* d_out, int out_size, void* d_ws, size_t ws_size,
                              hipStream_t stream) {
    const float* x  = (const float*)d_in[0];
    const int*   ei = (const int*)d_in[1];
    const int* src = ei;
    const int* dst = ei + NE;
    auto P = [&](int i) { return (const float*)d_in[i]; };

    const size_t BUFF = (size_t)NN * HD * sizeof(float);  // 51.2 MB fp32
    const size_t BUFH = (size_t)NN * HD * sizeof(u16);    // 25.6 MB bf16
    char* ws = (char*)d_ws;
    u16*   gB   = (u16*)(ws);                             // bf16 [NN][128] lin2 out
    u16*   aggB = (u16*)(ws + BUFH);                      // bf16 [NN][128] aggr out
    float* yF   = (float*)(ws + 2 * BUFH);                // fp32 [NN][128] lin1 out
    float* hF   = (float*)(ws + 2 * BUFH + BUFF);         // fp32 [NN][128] L2 out
    u16*   xb   = (u16*)(ws + 2 * BUFH + 2 * BUFF);       // bf16 [NN][64]
    char*  sb   = ws + 2 * BUFH + 2 * BUFF + (size_t)NN * 64 * sizeof(u16);
    float* partial = (float*)sb;                          // [GG][256]
    float* af = (float*)(sb + (size_t)GG * 256 * 4);
    float* bf = af + 128;
    int* bucketCnt  = (int*)(af + 256);                   // [NBKT]
    int* bucketBase = bucketCnt + NBKT + 1;               // [NBKT+1]
    int* bucketCur  = bucketBase + NBKT + 1;              // [NBKT]
    int* rowptr     = bucketCur + NBKT + 1;               // [NN+1]
    int* eidx       = rowptr + NN + 3;                    // [NE]
    int2* pairs     = (int2*)(((size_t)(eidx + NE) + 15) & ~(size_t)15);  // [NE]

    const int EBLK = (NE + 4095) / 4096;                  // 391

    // ---- build CSR (dst-sorted) via bucket sort ----
    hipMemsetAsync(bucketCnt, 0, NBKT * sizeof(int), stream);
    k_bcount<<<EBLK, 256, 0, stream>>>(dst, bucketCnt);
    k_bscan<<<1, 512, 0, stream>>>(bucketCnt, bucketBase, bucketCur);
    k_bscatter<<<EBLK, 256, 0, stream>>>(src, dst, bucketCur, pairs);
    k_bfinal<<<NBKT, 256, 0, stream>>>(pairs, bucketBase, rowptr, eidx);

    // ---- x -> bf16 ----
    k_cvt<<<2048, 256, 0, stream>>>(x, xb, NN * 64 / 4);

    // ---- layer 0 (K = 64) ----
    k_aggr<64><<<NN, 64, 0, stream>>>(xb, rowptr, eidx, P(8), aggB);
    k_gemm<64, 0, 0, 0, 1, 1><<<GG, 256, 0, stream>>>(
        aggB, nullptr, nullptr, P(2), P(3), yF, partial, nullptr, nullptr);
    k_bnfin2<<<128, 256, 0, stream>>>(partial, P(4), P(5), af, bf);
    k_gemm<128, 1, 1, 1, 0, 0><<<GG, 256, 0, stream>>>(
        yF, af, bf, P(6), P(7), gB, nullptr, nullptr, nullptr);

    // ---- layer 1 ----
    k_aggr<128><<<NN, 64, 0, stream>>>(gB, rowptr, eidx, P(15), aggB);
    k_gemm<128, 0, 0, 0, 1, 1><<<GG, 256, 0, stream>>>(
        aggB, nullptr, nullptr, P(9), P(10), yF, partial, nullptr, nullptr);
    k_bnfin2<<<128, 256, 0, stream>>>(partial, P(11), P(12), af, bf);
    k_gemm<128, 1, 1, 1, 0, 0><<<GG, 256, 0, stream>>>(
        yF, af, bf, P(13), P(14), gB, nullptr, nullptr, nullptr);

    // ---- layer 2 ----
    k_aggr<128><<<NN, 64, 0, stream>>>(gB, rowptr, eidx, P(22), aggB);
    k_gemm<128, 0, 0, 0, 1, 1><<<GG, 256, 0, stream>>>(
        aggB, nullptr, nullptr, P(16), P(17), yF, partial, nullptr, nullptr);
    k_bnfin2<<<128, 256, 0, stream>>>(partial, P(18), P(19), af, bf);
    k_gemm<128, 1, 1, 0, 0, 0><<<GG, 256, 0, stream>>>(
        yF, af, bf, P(20), P(21), hF, nullptr, nullptr, nullptr);

    // ---- head (lin1 + relu + lin2 fused) ----
    k_gemm<128, 0, 1, 2, 0, 0><<<GG, 256, 0, stream>>>(
        hF, nullptr, nullptr, P(23), P(24), (float*)d_out, nullptr, P(25), P(26));
}